// Round 3
// baseline (471.879 us; speedup 1.0000x reference)
//
#include <hip/hip_runtime.h>
#include <hip/hip_bf16.h>
#include <math.h>

#define DIM 64
#define BSHIFT 9
#define BNODES 512   // 1 << BSHIFT
#define MAXB 256     // max coarse buckets (N <= 131072)
#define EPT 8
#define CHUNK 2048   // EPT * 256

typedef __attribute__((ext_vector_type(8))) short bf16x8;
typedef __attribute__((ext_vector_type(4))) float f32x4;
typedef __attribute__((ext_vector_type(2))) float f32x2;

__device__ __forceinline__ short f2bf(float x) {
    union { __hip_bfloat16 b; short s; } u;
    u.b = __float2bfloat16(x);
    return u.s;
}
__device__ __forceinline__ float bf2f(short s) {
    return __uint_as_float(((unsigned)(unsigned short)s) << 16);
}
// d = a*b + d on a packed f32 pair (VOP3P); halves FMA issue count
__device__ __forceinline__ void pk_fma(f32x2& d, f32x2 a, f32x2 b) {
    asm("v_pk_fma_f32 %0, %1, %2, %0" : "+v"(d) : "v"(a), "v"(b));
}
__device__ __forceinline__ f32x2 shfl2(f32x2 v, int mask) {
    f32x2 r;
    r.x = __shfl_xor(v.x, mask, 64);
    r.y = __shfl_xor(v.y, mask, 64);
    return r;
}

// ---------------- CSR build: binned 2-pass sort ----------------

__global__ void bin_count_kernel(const int* __restrict__ dst, int* __restrict__ bucket_cnt, int E) {
    __shared__ int h[MAXB];
    int t = threadIdx.x;
    h[t] = 0;
    __syncthreads();
    for (int i = blockIdx.x * blockDim.x + t; i < E; i += gridDim.x * blockDim.x)
        atomicAdd(&h[dst[i] >> BSHIFT], 1);
    __syncthreads();
    if (h[t]) atomicAdd(&bucket_cnt[t], h[t]);
}

__global__ void bucket_scan_kernel(const int* __restrict__ bucket_cnt,
                                   int* __restrict__ bucket_off, int* __restrict__ bucket_fill) {
    __shared__ int s[MAXB];
    int t = threadIdx.x;
    int v = bucket_cnt[t];
    s[t] = v;
    __syncthreads();
    for (int off = 1; off < MAXB; off <<= 1) {
        int x = (t >= off) ? s[t - off] : 0;
        __syncthreads();
        s[t] += x;
        __syncthreads();
    }
    bucket_off[t] = s[t] - v;
    bucket_fill[t] = 0;
}

__global__ __launch_bounds__(256) void bin_scatter_kernel(
    const int* __restrict__ src, const int* __restrict__ dst,
    const int* __restrict__ bucket_off, int* __restrict__ bucket_fill,
    unsigned long long* __restrict__ binned, int E) {
    __shared__ int lcnt[MAXB];
    __shared__ int lbase[MAXB];
    int t = threadIdx.x;
    lcnt[t] = 0;
    __syncthreads();
    int base = blockIdx.x * CHUNK;
    unsigned long long pair[EPT];
    int slot[EPT];
#pragma unroll
    for (int j = 0; j < EPT; j++) {
        int idx = base + j * 256 + t;
        if (idx < E) {
            int s = src[idx], d = dst[idx];
            pair[j] = ((unsigned long long)(unsigned)d << 32) | (unsigned)s;
            slot[j] = atomicAdd(&lcnt[d >> BSHIFT], 1);
        } else {
            slot[j] = -1;
        }
    }
    __syncthreads();
    int c = lcnt[t];
    if (c) lbase[t] = atomicAdd(&bucket_fill[t], c);
    __syncthreads();
#pragma unroll
    for (int j = 0; j < EPT; j++) {
        if (slot[j] >= 0) {
            int b = (int)(pair[j] >> 32) >> BSHIFT;
            binned[(size_t)bucket_off[b] + lbase[b] + slot[j]] = pair[j];
        }
    }
}

__global__ __launch_bounds__(256) void node_count_kernel(
    const unsigned long long* __restrict__ binned, const int* __restrict__ bucket_off,
    const int* __restrict__ bucket_cnt, int* __restrict__ counts, int N) {
    __shared__ int cnt[BNODES];
    int b = blockIdx.x, t = threadIdx.x;
    for (int i = t; i < BNODES; i += 256) cnt[i] = 0;
    __syncthreads();
    int s0 = bucket_off[b], c = bucket_cnt[b];
    for (int i = t; i < c; i += 256) {
        int d = (int)(binned[(size_t)s0 + i] >> 32);
        atomicAdd(&cnt[d & (BNODES - 1)], 1);
    }
    __syncthreads();
    int nbase = b << BSHIFT;
    for (int i = t; i < BNODES; i += 256)
        if (nbase + i < N) counts[nbase + i] = cnt[i];
}

__global__ void scan1_kernel(const int* __restrict__ counts, int* __restrict__ excl,
                             int* __restrict__ blk_sums, int n) {
    __shared__ int sdata[256];
    int t = threadIdx.x;
    int base = blockIdx.x * 1024 + t * 4;
    int v0 = (base + 0 < n) ? counts[base + 0] : 0;
    int v1 = (base + 1 < n) ? counts[base + 1] : 0;
    int v2 = (base + 2 < n) ? counts[base + 2] : 0;
    int v3 = (base + 3 < n) ? counts[base + 3] : 0;
    int tsum = v0 + v1 + v2 + v3;
    sdata[t] = tsum;
    __syncthreads();
    for (int off = 1; off < 256; off <<= 1) {
        int x = (t >= off) ? sdata[t - off] : 0;
        __syncthreads();
        sdata[t] += x;
        __syncthreads();
    }
    int run = sdata[t] - tsum;
    if (base + 0 < n) excl[base + 0] = run; run += v0;
    if (base + 1 < n) excl[base + 1] = run; run += v1;
    if (base + 2 < n) excl[base + 2] = run; run += v2;
    if (base + 3 < n) excl[base + 3] = run;
    if (t == 255) blk_sums[blockIdx.x] = sdata[255];
}

__global__ void scan2_kernel(int* __restrict__ blk_sums, int nb) {
    __shared__ int s[128];
    int t = threadIdx.x;
    s[t] = (t < nb) ? blk_sums[t] : 0;
    __syncthreads();
    for (int off = 1; off < 128; off <<= 1) {
        int x = (t >= off) ? s[t - off] : 0;
        __syncthreads();
        s[t] += x;
        __syncthreads();
    }
    if (t < nb) blk_sums[t] = (t > 0) ? s[t - 1] : 0;
}

__global__ void scan3_kernel(int* __restrict__ excl, const int* __restrict__ blk_sums,
                             int n, int total) {
    int i = blockIdx.x * blockDim.x + threadIdx.x;
    if (i < n) excl[i] += blk_sums[i >> 10];
    if (i == 0) excl[n] = total;
}

__global__ __launch_bounds__(256) void final_scatter_kernel(
    const unsigned long long* __restrict__ binned, const int* __restrict__ bucket_off,
    const int* __restrict__ bucket_cnt, const int* __restrict__ row_ptr,
    int* __restrict__ src_sorted, int N) {
    __shared__ int fill[BNODES];
    int b = blockIdx.x, t = threadIdx.x;
    for (int i = t; i < BNODES; i += 256) fill[i] = 0;
    __syncthreads();
    int s0 = bucket_off[b], c = bucket_cnt[b];
    for (int i = t; i < c; i += 256) {
        unsigned long long p = binned[(size_t)s0 + i];
        int d = (int)(p >> 32);
        int pos = row_ptr[d] + atomicAdd(&fill[d & (BNODES - 1)], 1);
        src_sorted[pos] = (int)(p & 0xffffffffu);
    }
}

// ---------------- per-layer kernels ----------------

// Per-layer prep: wl = (W @ al) * log2e, wr = (W @ ar) * log2e.
// Lets the GEMM compute el = act(h).wl with 4 shuffles instead of a 32-shuffle
// epilogue, and lets attn use exp2 directly (no log2e mul per edge).
__global__ void wlr_kernel(
    const float* __restrict__ W1, const float* __restrict__ al1, const float* __restrict__ ar1,
    const float* __restrict__ W2, const float* __restrict__ al2, const float* __restrict__ ar2,
    const float* __restrict__ W3, const float* __restrict__ al3, const float* __restrict__ ar3,
    float* __restrict__ wlr) {
    const float* W  = (blockIdx.x == 0) ? W1  : (blockIdx.x == 1) ? W2  : W3;
    const float* al = (blockIdx.x == 0) ? al1 : (blockIdx.x == 1) ? al2 : al3;
    const float* ar = (blockIdx.x == 0) ? ar1 : (blockIdx.x == 1) ? ar2 : ar3;
    int k = threadIdx.x;   // 0..63
    float l = 0.f, r = 0.f;
    for (int nn = 0; nn < 64; nn++) {
        float w = W[k * 64 + nn];
        l = fmaf(w, al[nn], l);
        r = fmaf(w, ar[nn], r);
    }
    const float LOG2E = 1.4426950408889634f;
    wlr[blockIdx.x * 128 + k] = l * LOG2E;
    wlr[blockIdx.x * 128 + 64 + k] = r * LOG2E;
}

// MFMA GEMM: feat(bf16) = bnelu(h) @ W ; el = act.wl ; er = act.wr
// One wave per 16-row tile. W held in registers as hi/lo bf16 split-precision
// fragments; 3 MFMA passes give ~f32 accuracy.
// A-frag: A[m=lane&15][k=(lane>>4)*8+j]; B-frag: B[k=(lane>>4)*8+j][n=lane&15];
// C/D: row=(lane>>4)*4+reg, col=lane&15   [learn_hip m89-verified layouts]
__global__ __launch_bounds__(256) void gemm64_mfma_kernel(
    const float* __restrict__ h, const float* __restrict__ W,
    const float* __restrict__ wl, const float* __restrict__ wr,
    const float* __restrict__ stats, const float* __restrict__ g,
    const float* __restrict__ beta, int do_bn, float invN,
    __hip_bfloat16* __restrict__ feat, float* __restrict__ el, float* __restrict__ er,
    int n) {
    int t = threadIdx.x;
    int lane = t & 63;
    int li = lane & 15;
    int quad = lane >> 4;
    int wv = t >> 6;

    // B fragments (W is row-major W[k][n])
    bf16x8 b_hi[2][4], b_lo[2][4];
#pragma unroll
    for (int ks = 0; ks < 2; ks++)
#pragma unroll
        for (int nt = 0; nt < 4; nt++) {
#pragma unroll
            for (int j = 0; j < 8; j++) {
                float w = W[(ks * 32 + quad * 8 + j) * 64 + nt * 16 + li];
                short hi = f2bf(w);
                b_hi[ks][nt][j] = hi;
                b_lo[ks][nt][j] = f2bf(w - bf2f(hi));
            }
        }
    // wl/wr entries for the k-indices this lane's A-frag holds
    float wlv[2][8], wrv[2][8];
#pragma unroll
    for (int ks = 0; ks < 2; ks++)
#pragma unroll
        for (int j = 0; j < 8; j++) {
            wlv[ks][j] = wl[ks * 32 + quad * 8 + j];
            wrv[ks][j] = wr[ks * 32 + quad * 8 + j];
        }

    // BN scale/shift for input channels this lane touches: k = ks*32 + quad*8 + j
    float sc[2][8], sh[2][8];
    if (do_bn) {
#pragma unroll
        for (int ks = 0; ks < 2; ks++)
#pragma unroll
            for (int j = 0; j < 8; j++) {
                int k = ks * 32 + quad * 8 + j;
                float mu = stats[k] * invN;
                float var = fmaf(-mu, mu, stats[64 + k] * invN);
                float inv = rsqrtf(var + 1e-5f) * g[k];
                sc[ks][j] = inv;
                sh[ks][j] = beta[k] - mu * inv;
            }
    }

    int ntiles = (n + 15) >> 4;
    for (int tile = blockIdx.x * 4 + wv; tile < ntiles; tile += gridDim.x * 4) {
        int m0 = tile << 4;
        int rrow = m0 + li;
        const float* rowp = h + (size_t)((rrow < n) ? rrow : (n - 1)) * 64;
        bf16x8 a_hi[2], a_lo[2];
        float elp = 0.f, erp = 0.f;   // el/er partials on the f32 activations
#pragma unroll
        for (int ks = 0; ks < 2; ks++) {
            float4 v0 = *(const float4*)(rowp + ks * 32 + quad * 8);
            float4 v1 = *(const float4*)(rowp + ks * 32 + quad * 8 + 4);
            float x[8] = {v0.x, v0.y, v0.z, v0.w, v1.x, v1.y, v1.z, v1.w};
#pragma unroll
            for (int j = 0; j < 8; j++) {
                float v = x[j];
                if (do_bn) {
                    v = fmaf(v, sc[ks][j], sh[ks][j]);
                    if (v < 0.f) v = expm1f(v);   // ELU
                }
                elp = fmaf(v, wlv[ks][j], elp);
                erp = fmaf(v, wrv[ks][j], erp);
                short hi = f2bf(v);
                a_hi[ks][j] = hi;
                a_lo[ks][j] = f2bf(v - bf2f(hi));
            }
        }
        // el/er: A-frag row of this lane is m0+li; sum partials across the 4 quads
        elp += __shfl_xor(elp, 16, 64);
        elp += __shfl_xor(elp, 32, 64);
        erp += __shfl_xor(erp, 16, 64);
        erp += __shfl_xor(erp, 32, 64);
        if (lane < 16 && m0 + li < n) {
            el[m0 + li] = elp;
            er[m0 + li] = erp;
        }
        f32x4 acc[4];
#pragma unroll
        for (int nt = 0; nt < 4; nt++) acc[nt] = (f32x4){0.f, 0.f, 0.f, 0.f};
#pragma unroll
        for (int ks = 0; ks < 2; ks++)
#pragma unroll
            for (int nt = 0; nt < 4; nt++) {
                acc[nt] = __builtin_amdgcn_mfma_f32_16x16x32_bf16(a_hi[ks], b_hi[ks][nt], acc[nt], 0, 0, 0);
                acc[nt] = __builtin_amdgcn_mfma_f32_16x16x32_bf16(a_lo[ks], b_hi[ks][nt], acc[nt], 0, 0, 0);
                acc[nt] = __builtin_amdgcn_mfma_f32_16x16x32_bf16(a_hi[ks], b_lo[ks][nt], acc[nt], 0, 0, 0);
            }
        // feat store (bf16)
#pragma unroll
        for (int nt = 0; nt < 4; nt++)
#pragma unroll
            for (int reg = 0; reg < 4; reg++) {
                int wrow = m0 + quad * 4 + reg;
                if (wrow < n) {
                    union { __hip_bfloat16 b; short s; } u;
                    u.s = f2bf(acc[nt][reg]);
                    feat[(size_t)wrow * 64 + nt * 16 + li] = u.b;
                }
            }
    }
}

// Fused edge-score + softmax + weighted aggregate, one wave per dst node.
// 8 edge-slots (q) of 8 lanes (li); lane holds 8 dims via one uint4 (16B)
// bf16 gather. 2-deep pipeline: a degree-16 node has ALL gathers in flight
// before compute starts. el/er are pre-scaled by log2e -> exp2 directly.
// Invalid slots carry el=-inf -> w=exp2(-inf)=0 (no per-chunk mask select).
// Epilogue: 3-step reduce-scatter (each lane ends with one output dim) +
// one full-wave coalesced store.
__global__ __launch_bounds__(256) void attn_agg_kernel(
    const int* __restrict__ row_ptr, const int* __restrict__ src_sorted,
    const float* __restrict__ el, const float* __restrict__ er,
    const __hip_bfloat16* __restrict__ feat, const float* __restrict__ bias,
    float* __restrict__ out, int n) {
    int t = threadIdx.x, lane = t & 63;
    int q = lane >> 3;        // edge slot 0..7
    int li = lane & 7;        // dim octet 0..7
    int node = blockIdx.x * 4 + (t >> 6);
    if (node >= n) return;
    int start = row_ptr[node], end = row_ptr[node + 1];
    float er_n = er[node];
    const uint4* featv = (const uint4*)feat;

    float s = 0.f;
    f32x2 a01 = {0.f, 0.f}, a23 = {0.f, 0.f}, a45 = {0.f, 0.f}, a67 = {0.f, 0.f};

    uint4 p0 = {0u, 0u, 0u, 0u}, p1 = {0u, 0u, 0u, 0u};
    float el0 = -INFINITY, el1 = -INFINITY;
    if (start < end) {
        int idx = start + q;
        bool v = idx < end;
        int idc = v ? idx : end - 1;
        int sn = src_sorted[idc];
        float ev = el[sn];
        el0 = v ? ev : -INFINITY;
        p0 = featv[(size_t)sn * 8 + li];
    }
    if (start + 8 < end) {
        int idx = start + 8 + q;
        bool v = idx < end;
        int idc = v ? idx : end - 1;
        int sn = src_sorted[idc];
        float ev = el[sn];
        el1 = v ? ev : -INFINITY;
        p1 = featv[(size_t)sn * 8 + li];
    }
    for (int i = start; i < end; i += 8) {
        int i2 = i + 16;
        uint4 p2 = {0u, 0u, 0u, 0u};
        float el2 = -INFINITY;
        if (i2 < end) {                    // wave-uniform
            int idx = i2 + q;
            bool v = idx < end;
            int idc = v ? idx : end - 1;
            int sn = src_sorted[idc];
            float ev = el[sn];
            el2 = v ? ev : -INFINITY;
            p2 = featv[(size_t)sn * 8 + li];
        }
        float e = el0 + er_n;
        e = fmaxf(e, 0.2f * e);            // leaky relu (scale-invariant)
        float w = exp2f(e);                // inputs pre-scaled by log2e
        s += w;
        f32x2 ww = {w, w};
        f32x2 f;
        f.x = __uint_as_float(p0.x << 16); f.y = __uint_as_float(p0.x & 0xffff0000u);
        pk_fma(a01, ww, f);
        f.x = __uint_as_float(p0.y << 16); f.y = __uint_as_float(p0.y & 0xffff0000u);
        pk_fma(a23, ww, f);
        f.x = __uint_as_float(p0.z << 16); f.y = __uint_as_float(p0.z & 0xffff0000u);
        pk_fma(a45, ww, f);
        f.x = __uint_as_float(p0.w << 16); f.y = __uint_as_float(p0.w & 0xffff0000u);
        pk_fma(a67, ww, f);
        p0 = p1; el0 = el1; p1 = p2; el1 = el2;
    }
    // s: full butterfly over slots (all lanes need inv_s)
    s += __shfl_xor(s, 8, 64);
    s += __shfl_xor(s, 16, 64);
    s += __shfl_xor(s, 32, 64);
    // accumulators: reduce-scatter; lane (q,li) ends with dim
    // li*8 + 4*(q&1) + 2*((q>>1)&1) + ((q>>2)&1)
    f32x2 t01 = shfl2(a01, 8), t23 = shfl2(a23, 8);
    f32x2 t45 = shfl2(a45, 8), t67 = shfl2(a67, 8);
    bool b0 = (q & 1) != 0;
    f32x2 x = b0 ? (a45 + t45) : (a01 + t01);
    f32x2 y = b0 ? (a67 + t67) : (a23 + t23);
    f32x2 u = shfl2(x, 16), v2 = shfl2(y, 16);
    bool b1 = (q & 2) != 0;
    f32x2 z = b1 ? (y + v2) : (x + u);
    f32x2 zz = shfl2(z, 32);
    z = z + zz;
    float val = ((q & 4) != 0) ? z.y : z.x;
    int d = li * 8 + ((q & 1) << 2) + (q & 2) + ((q >> 2) & 1);
    float inv_s = (s > 0.f) ? 1.f / s : 0.f;
    out[(size_t)node * 64 + d] = fmaf(val, inv_s, bias[d]);
}

// column sums / sumsq
__global__ __launch_bounds__(256) void bn_stats_kernel(const float* __restrict__ h,
                                                       float* __restrict__ stats, int n) {
    __shared__ float ls[256], lss[256];
    int t = threadIdx.x, lane = t & 63;
    int w = blockIdx.x * 4 + (t >> 6);
    int stride = gridDim.x * 4;
    float s = 0.f, ss = 0.f;
    for (int row = w; row < n; row += stride) {
        float v = h[(size_t)row * DIM + lane];
        s += v;
        ss = fmaf(v, v, ss);
    }
    ls[t] = s; lss[t] = ss;
    __syncthreads();
    if (t < 64) {
        float a = ls[t] + ls[t + 64] + ls[t + 128] + ls[t + 192];
        float b = lss[t] + lss[t + 64] + lss[t + 128] + lss[t + 192];
        atomicAdd(&stats[t], a);
        atomicAdd(&stats[64 + t], b);
    }
}

__global__ void bn_apply_kernel(float* __restrict__ h, const float* __restrict__ stats,
                                const float* __restrict__ g, const float* __restrict__ beta,
                                int n, int do_elu) {
    int i = blockIdx.x * blockDim.x + threadIdx.x;
    int total = n * DIM;
    int stride = gridDim.x * blockDim.x;
    float invN = 1.f / (float)n;
    for (; i < total; i += stride) {
        int c = i & 63;
        float mu = stats[c] * invN;
        float var = fmaf(-mu, mu, stats[DIM + c] * invN);
        float x = (h[i] - mu) * rsqrtf(var + 1e-5f) * g[c] + beta[c];
        if (do_elu && x < 0.f) x = expm1f(x);
        h[i] = x;
    }
}

// ---------------- launch ----------------

extern "C" void kernel_launch(void* const* d_in, const int* in_sizes, int n_in,
                              void* d_out, int out_size, void* d_ws, size_t ws_size,
                              hipStream_t stream) {
    const float* nw = (const float*)d_in[0];
    const int* src = (const int*)d_in[2];
    const int* dst = (const int*)d_in[3];
    const int N = in_sizes[0] / DIM;
    const int E = in_sizes[2];
    const float invN = 1.f / (float)N;
    const int nbuck = (N + BNODES - 1) >> BSHIFT;

    char* ws = (char*)d_ws;
    size_t off = 0;
    auto alloc = [&](size_t bytes) -> void* {
        void* p = ws + off;
        off += (bytes + 255) & ~(size_t)255;
        return p;
    };
    int* counts       = (int*)alloc((size_t)N * 4);
    int* row_ptr      = (int*)alloc(((size_t)N + 1) * 4);
    int* blk_sums     = (int*)alloc(512);
    int* bucket_cnt   = (int*)alloc(MAXB * 4);
    int* bucket_off   = (int*)alloc(MAXB * 4);
    int* bucket_fill  = (int*)alloc(MAXB * 4);
    unsigned long long* binned = (unsigned long long*)alloc((size_t)E * 8);
    int* src_sorted   = (int*)alloc((size_t)E * 4);
    float* el         = (float*)alloc((size_t)N * 4);
    float* er         = (float*)alloc((size_t)N * 4);
    __hip_bfloat16* feat = (__hip_bfloat16*)alloc((size_t)N * DIM * 2);
    float* hbuf       = (float*)alloc((size_t)N * DIM * 4);
    float* stats      = (float*)alloc(3 * 512);   // 3 layer slots of 128 floats
    float* wlr        = (float*)alloc(3 * 128 * 4);

    int nb = (N + 1023) / 1024;

    // CSR build (once; same graph for all 3 layers) + per-layer wl/wr prep
    hipMemsetAsync(bucket_cnt, 0, MAXB * 4, stream);
    hipMemsetAsync(stats, 0, 3 * 512, stream);
    wlr_kernel<<<3, 64, 0, stream>>>(
        (const float*)d_in[4],  (const float*)d_in[5],  (const float*)d_in[6],
        (const float*)d_in[10], (const float*)d_in[11], (const float*)d_in[12],
        (const float*)d_in[16], (const float*)d_in[17], (const float*)d_in[18],
        wlr);
    bin_count_kernel<<<256, 256, 0, stream>>>(dst, bucket_cnt, E);
    bucket_scan_kernel<<<1, MAXB, 0, stream>>>(bucket_cnt, bucket_off, bucket_fill);
    bin_scatter_kernel<<<(E + CHUNK - 1) / CHUNK, 256, 0, stream>>>(
        src, dst, bucket_off, bucket_fill, binned, E);
    node_count_kernel<<<nbuck, 256, 0, stream>>>(binned, bucket_off, bucket_cnt, counts, N);
    scan1_kernel<<<nb, 256, 0, stream>>>(counts, row_ptr, blk_sums, N);
    scan2_kernel<<<1, 128, 0, stream>>>(blk_sums, nb);
    scan3_kernel<<<(N + 255) / 256, 256, 0, stream>>>(row_ptr, blk_sums, N, E);
    final_scatter_kernel<<<nbuck, 256, 0, stream>>>(binned, bucket_off, bucket_cnt,
                                                    row_ptr, src_sorted, N);

    for (int l = 0; l < 3; l++) {
        const float* b    = (const float*)d_in[7 + 6 * l];
        const float* hin = (l == 0) ? nw : hbuf;
        float* hout = (l == 2) ? (float*)d_out : hbuf;
        float* stats_prev = (l == 0) ? stats : stats + (l - 1) * 128;
        float* stats_cur  = stats + l * 128;

        gemm64_mfma_kernel<<<1024, 256, 0, stream>>>(
            hin, (const float*)d_in[4 + 6 * l],
            wlr + l * 128, wlr + l * 128 + 64,
            stats_prev,
            (l == 0) ? (const float*)d_in[8] : (const float*)d_in[8 + 6 * (l - 1)],
            (l == 0) ? (const float*)d_in[9] : (const float*)d_in[9 + 6 * (l - 1)],
            (l > 0) ? 1 : 0, invN,
            feat, el, er, N);
        attn_agg_kernel<<<(N + 3) / 4, 256, 0, stream>>>(row_ptr, src_sorted, el, er,
                                                         feat, b, hout, N);
        bn_stats_kernel<<<512, 256, 0, stream>>>(hout, stats_cur, N);
    }
    // final BatchNorm (no ELU) on d_out
    bn_apply_kernel<<<2048, 256, 0, stream>>>((float*)d_out, stats + 2 * 128,
                                              (const float*)d_in[8 + 12],
                                              (const float*)d_in[9 + 12],
                                              N, 0);
}

// Round 4
// 467.368 us; speedup vs baseline: 1.0097x; 1.0097x over previous
//
#include <hip/hip_runtime.h>
#include <hip/hip_bf16.h>
#include <math.h>

#define DIM 64
#define BSHIFT 9
#define BNODES 512   // 1 << BSHIFT
#define MAXB 256     // max coarse buckets (N <= 131072)
#define EPT 8
#define CHUNK 2048   // EPT * 256

typedef __attribute__((ext_vector_type(8))) short bf16x8;
typedef __attribute__((ext_vector_type(4))) float f32x4;

__device__ __forceinline__ short f2bf(float x) {
    union { __hip_bfloat16 b; short s; } u;
    u.b = __float2bfloat16(x);
    return u.s;
}
__device__ __forceinline__ float bf2f(short s) {
    return __uint_as_float(((unsigned)(unsigned short)s) << 16);
}

// ---------------- CSR build: binned 2-pass sort ----------------

__global__ void bin_count_kernel(const int* __restrict__ dst, int* __restrict__ bucket_cnt, int E) {
    __shared__ int h[MAXB];
    int t = threadIdx.x;
    h[t] = 0;
    __syncthreads();
    for (int i = blockIdx.x * blockDim.x + t; i < E; i += gridDim.x * blockDim.x)
        atomicAdd(&h[dst[i] >> BSHIFT], 1);
    __syncthreads();
    if (h[t]) atomicAdd(&bucket_cnt[t], h[t]);
}

__global__ void bucket_scan_kernel(const int* __restrict__ bucket_cnt,
                                   int* __restrict__ bucket_off, int* __restrict__ bucket_fill) {
    __shared__ int s[MAXB];
    int t = threadIdx.x;
    int v = bucket_cnt[t];
    s[t] = v;
    __syncthreads();
    for (int off = 1; off < MAXB; off <<= 1) {
        int x = (t >= off) ? s[t - off] : 0;
        __syncthreads();
        s[t] += x;
        __syncthreads();
    }
    bucket_off[t] = s[t] - v;
    bucket_fill[t] = 0;
}

__global__ __launch_bounds__(256) void bin_scatter_kernel(
    const int* __restrict__ src, const int* __restrict__ dst,
    const int* __restrict__ bucket_off, int* __restrict__ bucket_fill,
    unsigned long long* __restrict__ binned, int E) {
    __shared__ int lcnt[MAXB];
    __shared__ int lbase[MAXB];
    int t = threadIdx.x;
    lcnt[t] = 0;
    __syncthreads();
    int base = blockIdx.x * CHUNK;
    unsigned long long pair[EPT];
    int slot[EPT];
#pragma unroll
    for (int j = 0; j < EPT; j++) {
        int idx = base + j * 256 + t;
        if (idx < E) {
            int s = src[idx], d = dst[idx];
            pair[j] = ((unsigned long long)(unsigned)d << 32) | (unsigned)s;
            slot[j] = atomicAdd(&lcnt[d >> BSHIFT], 1);
        } else {
            slot[j] = -1;
        }
    }
    __syncthreads();
    int c = lcnt[t];
    if (c) lbase[t] = atomicAdd(&bucket_fill[t], c);
    __syncthreads();
#pragma unroll
    for (int j = 0; j < EPT; j++) {
        if (slot[j] >= 0) {
            int b = (int)(pair[j] >> 32) >> BSHIFT;
            binned[(size_t)bucket_off[b] + lbase[b] + slot[j]] = pair[j];
        }
    }
}

__global__ __launch_bounds__(256) void node_count_kernel(
    const unsigned long long* __restrict__ binned, const int* __restrict__ bucket_off,
    const int* __restrict__ bucket_cnt, int* __restrict__ counts, int N) {
    __shared__ int cnt[BNODES];
    int b = blockIdx.x, t = threadIdx.x;
    for (int i = t; i < BNODES; i += 256) cnt[i] = 0;
    __syncthreads();
    int s0 = bucket_off[b], c = bucket_cnt[b];
    for (int i = t; i < c; i += 256) {
        int d = (int)(binned[(size_t)s0 + i] >> 32);
        atomicAdd(&cnt[d & (BNODES - 1)], 1);
    }
    __syncthreads();
    int nbase = b << BSHIFT;
    for (int i = t; i < BNODES; i += 256)
        if (nbase + i < N) counts[nbase + i] = cnt[i];
}

__global__ void scan1_kernel(const int* __restrict__ counts, int* __restrict__ excl,
                             int* __restrict__ blk_sums, int n) {
    __shared__ int sdata[256];
    int t = threadIdx.x;
    int base = blockIdx.x * 1024 + t * 4;
    int v0 = (base + 0 < n) ? counts[base + 0] : 0;
    int v1 = (base + 1 < n) ? counts[base + 1] : 0;
    int v2 = (base + 2 < n) ? counts[base + 2] : 0;
    int v3 = (base + 3 < n) ? counts[base + 3] : 0;
    int tsum = v0 + v1 + v2 + v3;
    sdata[t] = tsum;
    __syncthreads();
    for (int off = 1; off < 256; off <<= 1) {
        int x = (t >= off) ? sdata[t - off] : 0;
        __syncthreads();
        sdata[t] += x;
        __syncthreads();
    }
    int run = sdata[t] - tsum;
    if (base + 0 < n) excl[base + 0] = run; run += v0;
    if (base + 1 < n) excl[base + 1] = run; run += v1;
    if (base + 2 < n) excl[base + 2] = run; run += v2;
    if (base + 3 < n) excl[base + 3] = run;
    if (t == 255) blk_sums[blockIdx.x] = sdata[255];
}

__global__ void scan2_kernel(int* __restrict__ blk_sums, int nb) {
    __shared__ int s[128];
    int t = threadIdx.x;
    s[t] = (t < nb) ? blk_sums[t] : 0;
    __syncthreads();
    for (int off = 1; off < 128; off <<= 1) {
        int x = (t >= off) ? s[t - off] : 0;
        __syncthreads();
        s[t] += x;
        __syncthreads();
    }
    if (t < nb) blk_sums[t] = (t > 0) ? s[t - 1] : 0;
}

__global__ void scan3_kernel(int* __restrict__ excl, const int* __restrict__ blk_sums,
                             int n, int total) {
    int i = blockIdx.x * blockDim.x + threadIdx.x;
    if (i < n) excl[i] += blk_sums[i >> 10];
    if (i == 0) excl[n] = total;
}

__global__ __launch_bounds__(256) void final_scatter_kernel(
    const unsigned long long* __restrict__ binned, const int* __restrict__ bucket_off,
    const int* __restrict__ bucket_cnt, const int* __restrict__ row_ptr,
    int* __restrict__ src_sorted, int N) {
    __shared__ int fill[BNODES];
    int b = blockIdx.x, t = threadIdx.x;
    for (int i = t; i < BNODES; i += 256) fill[i] = 0;
    __syncthreads();
    int s0 = bucket_off[b], c = bucket_cnt[b];
    for (int i = t; i < c; i += 256) {
        unsigned long long p = binned[(size_t)s0 + i];
        int d = (int)(p >> 32);
        int pos = row_ptr[d] + atomicAdd(&fill[d & (BNODES - 1)], 1);
        src_sorted[pos] = (int)(p & 0xffffffffu);
    }
}

// ---------------- per-layer kernels ----------------

// Per-layer prep (runs once, 3 blocks):
//  wl = (W @ al) * log2e, wr = (W @ ar) * log2e  (attn uses exp2 directly)
//  whi/wlo: split-precision bf16 W fragments PRE-PACKED in the gemm wave's
//  fragment layout, so the gemm prologue is 16x 16B loads instead of
//  64 scalar loads + 128 cvts per wave (setup was ~40% of gemm at 1.5
//  tiles/wave).
//  frag layout: idx = ((ks*4+nt)*4+quad)*128 + li*8 + j  ->
//               W[(ks*32+quad*8+j)*64 + nt*16+li]
__global__ void wlr_kernel(
    const float* __restrict__ W1, const float* __restrict__ al1, const float* __restrict__ ar1,
    const float* __restrict__ W2, const float* __restrict__ al2, const float* __restrict__ ar2,
    const float* __restrict__ W3, const float* __restrict__ al3, const float* __restrict__ ar3,
    float* __restrict__ wlr, short* __restrict__ wfrag) {
    const float* W  = (blockIdx.x == 0) ? W1  : (blockIdx.x == 1) ? W2  : W3;
    const float* al = (blockIdx.x == 0) ? al1 : (blockIdx.x == 1) ? al2 : al3;
    const float* ar = (blockIdx.x == 0) ? ar1 : (blockIdx.x == 1) ? ar2 : ar3;
    int t = threadIdx.x;
    short* whi = wfrag + blockIdx.x * 8192;
    short* wlo = whi + 4096;
    for (int idx = t; idx < 4096; idx += 256) {
        int j = idx & 7, li = (idx >> 3) & 15, quad = (idx >> 7) & 3;
        int nt = (idx >> 9) & 3, ks = idx >> 11;
        int k = ks * 32 + quad * 8 + j, nn = nt * 16 + li;
        float w = W[k * 64 + nn];
        short hi = f2bf(w);
        whi[idx] = hi;
        wlo[idx] = f2bf(w - bf2f(hi));
    }
    if (t < 64) {
        float l = 0.f, r = 0.f;
        for (int nn = 0; nn < 64; nn++) {
            float w = W[t * 64 + nn];
            l = fmaf(w, al[nn], l);
            r = fmaf(w, ar[nn], r);
        }
        const float LOG2E = 1.4426950408889634f;
        wlr[blockIdx.x * 128 + t] = l * LOG2E;
        wlr[blockIdx.x * 128 + 64 + t] = r * LOG2E;
    }
}

// MFMA GEMM: feat(bf16) = bnelu(h) @ W ; el = act.wl ; er = act.wr
// One wave per 16-row tile. W fragments vector-loaded pre-packed (wlr_kernel).
// A-frag: A[m=lane&15][k=(lane>>4)*8+j]; B-frag: B[k=(lane>>4)*8+j][n=lane&15];
// C/D: row=(lane>>4)*4+reg, col=lane&15   [learn_hip m89-verified layouts]
__global__ __launch_bounds__(256) void gemm64_mfma_kernel(
    const float* __restrict__ h, const short* __restrict__ wfrag_l,
    const float* __restrict__ wl, const float* __restrict__ wr,
    const float* __restrict__ stats, const float* __restrict__ g,
    const float* __restrict__ beta, int do_bn, float invN,
    __hip_bfloat16* __restrict__ feat, float* __restrict__ el, float* __restrict__ er,
    int n) {
    int t = threadIdx.x;
    int lane = t & 63;
    int li = lane & 15;
    int quad = lane >> 4;
    int wv = t >> 6;

    // B fragments: 16 contiguous 16B loads (pre-packed hi/lo split)
    const short* whi = wfrag_l;
    const short* wlo = wfrag_l + 4096;
    bf16x8 b_hi[2][4], b_lo[2][4];
#pragma unroll
    for (int ks = 0; ks < 2; ks++)
#pragma unroll
        for (int nt = 0; nt < 4; nt++) {
            int base = (((ks * 4 + nt) * 4 + quad) * 16 + li) * 8;
            b_hi[ks][nt] = *(const bf16x8*)(whi + base);
            b_lo[ks][nt] = *(const bf16x8*)(wlo + base);
        }
    // wl/wr entries for the k-indices this lane's A-frag holds
    float wlv[2][8], wrv[2][8];
#pragma unroll
    for (int ks = 0; ks < 2; ks++)
#pragma unroll
        for (int j = 0; j < 8; j++) {
            wlv[ks][j] = wl[ks * 32 + quad * 8 + j];
            wrv[ks][j] = wr[ks * 32 + quad * 8 + j];
        }

    // BN scale/shift for input channels this lane touches: k = ks*32 + quad*8 + j
    float sc[2][8], sh[2][8];
    if (do_bn) {
#pragma unroll
        for (int ks = 0; ks < 2; ks++)
#pragma unroll
            for (int j = 0; j < 8; j++) {
                int k = ks * 32 + quad * 8 + j;
                float mu = stats[k] * invN;
                float var = fmaf(-mu, mu, stats[64 + k] * invN);
                float inv = rsqrtf(var + 1e-5f) * g[k];
                sc[ks][j] = inv;
                sh[ks][j] = beta[k] - mu * inv;
            }
    }

    int ntiles = (n + 15) >> 4;
    for (int tile = blockIdx.x * 4 + wv; tile < ntiles; tile += gridDim.x * 4) {
        int m0 = tile << 4;
        int rrow = m0 + li;
        const float* rowp = h + (size_t)((rrow < n) ? rrow : (n - 1)) * 64;
        bf16x8 a_hi[2], a_lo[2];
        float elp = 0.f, erp = 0.f;   // el/er partials on the f32 activations
#pragma unroll
        for (int ks = 0; ks < 2; ks++) {
            float4 v0 = *(const float4*)(rowp + ks * 32 + quad * 8);
            float4 v1 = *(const float4*)(rowp + ks * 32 + quad * 8 + 4);
            float x[8] = {v0.x, v0.y, v0.z, v0.w, v1.x, v1.y, v1.z, v1.w};
#pragma unroll
            for (int j = 0; j < 8; j++) {
                float v = x[j];
                if (do_bn) {
                    v = fmaf(v, sc[ks][j], sh[ks][j]);
                    if (v < 0.f) v = expm1f(v);   // ELU
                }
                elp = fmaf(v, wlv[ks][j], elp);
                erp = fmaf(v, wrv[ks][j], erp);
                short hi = f2bf(v);
                a_hi[ks][j] = hi;
                a_lo[ks][j] = f2bf(v - bf2f(hi));
            }
        }
        // el/er: A-frag row of this lane is m0+li; sum partials across the 4 quads
        elp += __shfl_xor(elp, 16, 64);
        elp += __shfl_xor(elp, 32, 64);
        erp += __shfl_xor(erp, 16, 64);
        erp += __shfl_xor(erp, 32, 64);
        if (lane < 16 && m0 + li < n) {
            el[m0 + li] = elp;
            er[m0 + li] = erp;
        }
        f32x4 acc[4];
#pragma unroll
        for (int nt = 0; nt < 4; nt++) acc[nt] = (f32x4){0.f, 0.f, 0.f, 0.f};
#pragma unroll
        for (int ks = 0; ks < 2; ks++)
#pragma unroll
            for (int nt = 0; nt < 4; nt++) {
                acc[nt] = __builtin_amdgcn_mfma_f32_16x16x32_bf16(a_hi[ks], b_hi[ks][nt], acc[nt], 0, 0, 0);
                acc[nt] = __builtin_amdgcn_mfma_f32_16x16x32_bf16(a_lo[ks], b_hi[ks][nt], acc[nt], 0, 0, 0);
                acc[nt] = __builtin_amdgcn_mfma_f32_16x16x32_bf16(a_hi[ks], b_lo[ks][nt], acc[nt], 0, 0, 0);
            }
        // feat store (bf16)
#pragma unroll
        for (int nt = 0; nt < 4; nt++)
#pragma unroll
            for (int reg = 0; reg < 4; reg++) {
                int wrow = m0 + quad * 4 + reg;
                if (wrow < n) {
                    union { __hip_bfloat16 b; short s; } u;
                    u.s = f2bf(acc[nt][reg]);
                    feat[(size_t)wrow * 64 + nt * 16 + li] = u.b;
                }
            }
    }
}

// Fused edge-score + softmax + weighted aggregate, one wave per dst node.
// 8 edge-slots (q) of 8 lanes (li); lane holds 8 dims via one uint4 (16B)
// bf16 gather. 2-deep ping-pong prefetch with NAMED buffers pA/pB (no
// rotation v_movs -- round-3 lesson: pk_fma + rotating uint4 pipeline
// RAISED VALUBusy 58->73%). el/er pre-scaled by log2e -> exp2f (native
// v_exp_f32). Invalid slots carry el=-inf -> w=0. Epilogue: 3-step scalar
// reduce-scatter; each lane ends with one output dim -> one coalesced store.
#define AGG_LOAD(P, ELV, POS)                                  \
    {                                                          \
        int idx = (POS) + q;                                   \
        bool v = idx < end;                                    \
        int idc = v ? idx : end - 1;                           \
        int sn = src_sorted[idc];                              \
        float ev = el[sn];                                     \
        ELV = v ? ev : -INFINITY;                              \
        P = featv[(size_t)sn * 8 + li];                        \
    }

#define AGG_CHUNK(P, ELV)                                      \
    {                                                          \
        float e = ELV + er_n;                                  \
        e = fmaxf(e, 0.2f * e);                                \
        float w = exp2f(e);                                    \
        s += w;                                                \
        a0 = fmaf(w, __uint_as_float(P.x << 16), a0);          \
        a1 = fmaf(w, __uint_as_float(P.x & 0xffff0000u), a1);  \
        a2 = fmaf(w, __uint_as_float(P.y << 16), a2);          \
        a3 = fmaf(w, __uint_as_float(P.y & 0xffff0000u), a3);  \
        a4 = fmaf(w, __uint_as_float(P.z << 16), a4);          \
        a5 = fmaf(w, __uint_as_float(P.z & 0xffff0000u), a5);  \
        a6 = fmaf(w, __uint_as_float(P.w << 16), a6);          \
        a7 = fmaf(w, __uint_as_float(P.w & 0xffff0000u), a7);  \
    }

__global__ __launch_bounds__(256) void attn_agg_kernel(
    const int* __restrict__ row_ptr, const int* __restrict__ src_sorted,
    const float* __restrict__ el, const float* __restrict__ er,
    const __hip_bfloat16* __restrict__ feat, const float* __restrict__ bias,
    float* __restrict__ out, int n) {
    int t = threadIdx.x, lane = t & 63;
    int q = lane >> 3;        // edge slot 0..7
    int li = lane & 7;        // dim octet 0..7
    int node = blockIdx.x * 4 + (t >> 6);
    if (node >= n) return;
    int start = row_ptr[node], end = row_ptr[node + 1];
    float er_n = er[node];
    const uint4* featv = (const uint4*)feat;

    float s = 0.f;
    float a0 = 0.f, a1 = 0.f, a2 = 0.f, a3 = 0.f;
    float a4 = 0.f, a5 = 0.f, a6 = 0.f, a7 = 0.f;

    uint4 pA = {0u, 0u, 0u, 0u}, pB = {0u, 0u, 0u, 0u};
    float elA = -INFINITY, elB = -INFINITY;
    if (start < end) AGG_LOAD(pA, elA, start)
    if (start + 8 < end) AGG_LOAD(pB, elB, start + 8)
    for (int i = start; i < end; i += 16) {      // all branches wave-uniform
        AGG_CHUNK(pA, elA)
        if (i + 16 < end) AGG_LOAD(pA, elA, i + 16)
        if (i + 8 < end) {
            AGG_CHUNK(pB, elB)
            if (i + 24 < end) AGG_LOAD(pB, elB, i + 24)
        }
    }
    // s: full butterfly over slots (all lanes need inv_s)
    s += __shfl_xor(s, 8, 64);
    s += __shfl_xor(s, 16, 64);
    s += __shfl_xor(s, 32, 64);
    // reduce-scatter: lane (q,li) ends with dim li*8 + 4*(q&1) + (q&2) + ((q>>2)&1)
    bool b0 = (q & 1) != 0;
    float t0 = __shfl_xor(a0, 8, 64), t1 = __shfl_xor(a1, 8, 64);
    float t2 = __shfl_xor(a2, 8, 64), t3 = __shfl_xor(a3, 8, 64);
    float t4 = __shfl_xor(a4, 8, 64), t5 = __shfl_xor(a5, 8, 64);
    float t6 = __shfl_xor(a6, 8, 64), t7 = __shfl_xor(a7, 8, 64);
    float x0 = b0 ? (a4 + t4) : (a0 + t0);
    float x1 = b0 ? (a5 + t5) : (a1 + t1);
    float y0 = b0 ? (a6 + t6) : (a2 + t2);
    float y1 = b0 ? (a7 + t7) : (a3 + t3);
    bool b1 = (q & 2) != 0;
    float u0 = __shfl_xor(x0, 16, 64), u1 = __shfl_xor(x1, 16, 64);
    float v0 = __shfl_xor(y0, 16, 64), v1 = __shfl_xor(y1, 16, 64);
    float z0 = b1 ? (y0 + v0) : (x0 + u0);
    float z1 = b1 ? (y1 + v1) : (x1 + u1);
    z0 += __shfl_xor(z0, 32, 64);
    z1 += __shfl_xor(z1, 32, 64);
    float val = ((q & 4) != 0) ? z1 : z0;
    int d = li * 8 + ((q & 1) << 2) + (q & 2) + ((q >> 2) & 1);
    float inv_s = (s > 0.f) ? 1.f / s : 0.f;
    out[(size_t)node * 64 + d] = fmaf(val, inv_s, bias[d]);
}

// column sums / sumsq
__global__ __launch_bounds__(256) void bn_stats_kernel(const float* __restrict__ h,
                                                       float* __restrict__ stats, int n) {
    __shared__ float ls[256], lss[256];
    int t = threadIdx.x, lane = t & 63;
    int w = blockIdx.x * 4 + (t >> 6);
    int stride = gridDim.x * 4;
    float s = 0.f, ss = 0.f;
    for (int row = w; row < n; row += stride) {
        float v = h[(size_t)row * DIM + lane];
        s += v;
        ss = fmaf(v, v, ss);
    }
    ls[t] = s; lss[t] = ss;
    __syncthreads();
    if (t < 64) {
        float a = ls[t] + ls[t + 64] + ls[t + 128] + ls[t + 192];
        float b = lss[t] + lss[t + 64] + lss[t + 128] + lss[t + 192];
        atomicAdd(&stats[t], a);
        atomicAdd(&stats[64 + t], b);
    }
}

__global__ void bn_apply_kernel(float* __restrict__ h, const float* __restrict__ stats,
                                const float* __restrict__ g, const float* __restrict__ beta,
                                int n, int do_elu) {
    int i = blockIdx.x * blockDim.x + threadIdx.x;
    int total = n * DIM;
    int stride = gridDim.x * blockDim.x;
    float invN = 1.f / (float)n;
    for (; i < total; i += stride) {
        int c = i & 63;
        float mu = stats[c] * invN;
        float var = fmaf(-mu, mu, stats[DIM + c] * invN);
        float x = (h[i] - mu) * rsqrtf(var + 1e-5f) * g[c] + beta[c];
        if (do_elu && x < 0.f) x = expm1f(x);
        h[i] = x;
    }
}

// ---------------- launch ----------------

extern "C" void kernel_launch(void* const* d_in, const int* in_sizes, int n_in,
                              void* d_out, int out_size, void* d_ws, size_t ws_size,
                              hipStream_t stream) {
    const float* nw = (const float*)d_in[0];
    const int* src = (const int*)d_in[2];
    const int* dst = (const int*)d_in[3];
    const int N = in_sizes[0] / DIM;
    const int E = in_sizes[2];
    const float invN = 1.f / (float)N;
    const int nbuck = (N + BNODES - 1) >> BSHIFT;

    char* ws = (char*)d_ws;
    size_t off = 0;
    auto alloc = [&](size_t bytes) -> void* {
        void* p = ws + off;
        off += (bytes + 255) & ~(size_t)255;
        return p;
    };
    int* counts       = (int*)alloc((size_t)N * 4);
    int* row_ptr      = (int*)alloc(((size_t)N + 1) * 4);
    int* blk_sums     = (int*)alloc(512);
    int* bucket_cnt   = (int*)alloc(MAXB * 4);
    int* bucket_off   = (int*)alloc(MAXB * 4);
    int* bucket_fill  = (int*)alloc(MAXB * 4);
    unsigned long long* binned = (unsigned long long*)alloc((size_t)E * 8);
    int* src_sorted   = (int*)alloc((size_t)E * 4);
    float* el         = (float*)alloc((size_t)N * 4);
    float* er         = (float*)alloc((size_t)N * 4);
    __hip_bfloat16* feat = (__hip_bfloat16*)alloc((size_t)N * DIM * 2);
    float* hbuf       = (float*)alloc((size_t)N * DIM * 4);
    float* stats      = (float*)alloc(3 * 512);     // 3 layer slots of 128 floats
    float* wlr        = (float*)alloc(3 * 128 * 4);
    short* wfrag      = (short*)alloc(3 * 8192 * 2); // [layer][hi/lo][4096] bf16

    int nb = (N + 1023) / 1024;

    // CSR build (once; same graph for all 3 layers) + per-layer W prep
    hipMemsetAsync(bucket_cnt, 0, MAXB * 4, stream);
    hipMemsetAsync(stats, 0, 3 * 512, stream);
    wlr_kernel<<<3, 256, 0, stream>>>(
        (const float*)d_in[4],  (const float*)d_in[5],  (const float*)d_in[6],
        (const float*)d_in[10], (const float*)d_in[11], (const float*)d_in[12],
        (const float*)d_in[16], (const float*)d_in[17], (const float*)d_in[18],
        wlr, wfrag);
    bin_count_kernel<<<256, 256, 0, stream>>>(dst, bucket_cnt, E);
    bucket_scan_kernel<<<1, MAXB, 0, stream>>>(bucket_cnt, bucket_off, bucket_fill);
    bin_scatter_kernel<<<(E + CHUNK - 1) / CHUNK, 256, 0, stream>>>(
        src, dst, bucket_off, bucket_fill, binned, E);
    node_count_kernel<<<nbuck, 256, 0, stream>>>(binned, bucket_off, bucket_cnt, counts, N);
    scan1_kernel<<<nb, 256, 0, stream>>>(counts, row_ptr, blk_sums, N);
    scan2_kernel<<<1, 128, 0, stream>>>(blk_sums, nb);
    scan3_kernel<<<(N + 255) / 256, 256, 0, stream>>>(row_ptr, blk_sums, N, E);
    final_scatter_kernel<<<nbuck, 256, 0, stream>>>(binned, bucket_off, bucket_cnt,
                                                    row_ptr, src_sorted, N);

    for (int l = 0; l < 3; l++) {
        const float* b    = (const float*)d_in[7 + 6 * l];
        const float* hin = (l == 0) ? nw : hbuf;
        float* hout = (l == 2) ? (float*)d_out : hbuf;
        float* stats_prev = (l == 0) ? stats : stats + (l - 1) * 128;
        float* stats_cur  = stats + l * 128;

        gemm64_mfma_kernel<<<1024, 256, 0, stream>>>(
            hin, wfrag + l * 8192,
            wlr + l * 128, wlr + l * 128 + 64,
            stats_prev,
            (l == 0) ? (const float*)d_in[8] : (const float*)d_in[8 + 6 * (l - 1)],
            (l == 0) ? (const float*)d_in[9] : (const float*)d_in[9 + 6 * (l - 1)],
            (l > 0) ? 1 : 0, invN,
            feat, el, er, N);
        attn_agg_kernel<<<(N + 3) / 4, 256, 0, stream>>>(row_ptr, src_sorted, el, er,
                                                         feat, b, hout, N);
        bn_stats_kernel<<<512, 256, 0, stream>>>(hout, stats_cur, N);
    }
    // final BatchNorm (no ELU) on d_out
    bn_apply_kernel<<<2048, 256, 0, stream>>>((float*)d_out, stats + 2 * 128,
                                              (const float*)d_in[8 + 12],
                                              (const float*)d_in[9 + 12],
                                              N, 0);
}